// Round 3
// baseline (359.310 us; speedup 1.0000x reference)
//
#include <hip/hip_runtime.h>
#include <math.h>

#define NFEAT 128
#define NGRAPHS 2048

// Online-softmax update for one float4 (4 features owned by this lane).
__device__ __forceinline__ void update4(const float4& v, float p,
                                        float* m, float* d, float* num) {
    float vals[4] = {v.x, v.y, v.z, v.w};
#pragma unroll
    for (int j = 0; j < 4; ++j) {
        float l = p * vals[j];
        float mn = fmaxf(m[j], l);
        float sc = __expf(m[j] - mn);  // 1 when max unchanged; 0 on first row
        float t = __expf(l - mn);
        d[j] = d[j] * sc + t;
        num[j] = num[j] * sc + vals[j] * t;
        m[j] = mn;
    }
}

// One block per graph. Segment bounds found by per-block binary search on the
// sorted batch array (2 MB -> L2/L3 resident; 19 probes x 2 threads, hidden).
// Single pass over the graph's rows with a branch-free 4-deep unrolled loop:
// lane = tid&31 owns features [4*lane,4*lane+4) (float4, 16 B/lane, wave's 64
// lanes cover 2 adjacent rows = 1 KiB contiguous); rg = tid>>5 strides rows.
__global__ __launch_bounds__(256) void pool_kernel(
    const float* __restrict__ x, const int* __restrict__ batch, int n,
    const float* __restrict__ p_ptr, const float* __restrict__ beta_ptr,
    float* __restrict__ out) {
    const int g = blockIdx.x;

    __shared__ int sbounds[2];
    if (threadIdx.x < 2) {
        const int target = g + (int)threadIdx.x;
        int lo = 0, hi = n;  // first i with batch[i] >= target
        while (lo < hi) {
            int mid = (lo + hi) >> 1;
            if (batch[mid] < target) lo = mid + 1; else hi = mid;
        }
        sbounds[threadIdx.x] = lo;
    }
    __syncthreads();
    const int s = sbounds[0];
    const int e = sbounds[1];
    const int cnt = e - s;
    const float p = p_ptr[0];
    const float beta = beta_ptr[0];

    const int lane = threadIdx.x & 31;  // feature-quad index (0..31)
    const int rg = threadIdx.x >> 5;    // row group (0..7)

    float m[4], d[4], num[4];
#pragma unroll
    for (int j = 0; j < 4; ++j) {
        m[j] = -INFINITY;
        d[j] = 0.0f;
        num[j] = 0.0f;
    }

    const float* __restrict__ bp = x + (size_t)s * NFEAT + lane * 4;

    int r = rg;
    // Main loop: 4 rows per thread per iteration, no conditional loads.
    for (; r + 24 < cnt; r += 32) {
        const float4 c0 = *(const float4*)(bp + (size_t)(r     ) * NFEAT);
        const float4 c1 = *(const float4*)(bp + (size_t)(r +  8) * NFEAT);
        const float4 c2 = *(const float4*)(bp + (size_t)(r + 16) * NFEAT);
        const float4 c3 = *(const float4*)(bp + (size_t)(r + 24) * NFEAT);
        update4(c0, p, m, d, num);
        update4(c1, p, m, d, num);
        update4(c2, p, m, d, num);
        update4(c3, p, m, d, num);
    }
    // Remainder (<= 3 rows per thread).
    for (; r < cnt; r += 8) {
        const float4 c0 = *(const float4*)(bp + (size_t)r * NFEAT);
        update4(c0, p, m, d, num);
    }

    // Combine the 8 row-group partial softmax states per feature via LDS.
    __shared__ float sm[8][NFEAT];
    __shared__ float sd[8][NFEAT];
    __shared__ float sn[8][NFEAT];
#pragma unroll
    for (int j = 0; j < 4; ++j) {
        sm[rg][lane * 4 + j] = m[j];
        sd[rg][lane * 4 + j] = d[j];
        sn[rg][lane * 4 + j] = num[j];
    }
    __syncthreads();

    if (threadIdx.x < NFEAT) {
        const int f = threadIdx.x;
        float M = sm[0][f], D = sd[0][f], Nm = sn[0][f];
#pragma unroll
        for (int k = 1; k < 8; ++k) {
            float m2 = sm[k][f];
            float Mn = fmaxf(M, m2);
            float s1 = __expf(M - Mn);
            float s2 = __expf(m2 - Mn);
            D = D * s1 + sd[k][f] * s2;
            Nm = Nm * s1 + sn[k][f] * s2;
            M = Mn;
        }
        float nn = (float)cnt;
        float rescale = nn / (1.0f + beta * (nn - 1.0f));
        out[(size_t)g * NFEAT + f] = (Nm / D) * rescale;
    }
}

extern "C" void kernel_launch(void* const* d_in, const int* in_sizes, int n_in,
                              void* d_out, int out_size, void* d_ws, size_t ws_size,
                              hipStream_t stream) {
    const float* x = (const float*)d_in[0];
    const int* batch = (const int*)d_in[1];
    const float* p = (const float*)d_in[2];
    const float* beta = (const float*)d_in[3];
    float* out = (float*)d_out;
    (void)d_ws; (void)ws_size;

    const int n = in_sizes[0] / NFEAT;  // 500000

    pool_kernel<<<NGRAPHS, 256, 0, stream>>>(x, batch, n, p, beta, out);
}